// Round 1
// baseline (111.145 us; speedup 1.0000x reference)
//
#include <hip/hip_runtime.h>

#define B_SZ 32
#define D_CH 96
#define L_SZ 4096   // 64*64
#define N_ST 4
#define R_RK 6

static __device__ __forceinline__ float softplus_f(float v) {
    return fmaxf(v, 0.0f) + __logf(1.0f + __expf(-fabsf(v)));
}

static __device__ __forceinline__ float exp2_fast(float x) {
#if __has_builtin(__builtin_amdgcn_exp2f)
    return __builtin_amdgcn_exp2f(x);      // v_exp_f32 (native 2^x)
#else
    return __expf(x * 0.6931471805599453f);
#endif
}

// DPP-shifted add: v + dpp(v); no LDS, no lgkm wait.
template<int CTRL, int RMASK>
static __device__ __forceinline__ float dpp_add(float v) {
    const int t = __builtin_amdgcn_update_dpp(0, __float_as_int(v),
                                              CTRL, RMASK, 0xf, true);
    return v + __int_as_float(t);
}

// wave64 inclusive scan (classic 6-step GCN sequence), pure VALU.
static __device__ __forceinline__ float wave_incl_scan(float v) {
    v = dpp_add<0x111, 0xf>(v);   // row_shr:1
    v = dpp_add<0x112, 0xf>(v);   // row_shr:2
    v = dpp_add<0x114, 0xf>(v);   // row_shr:4
    v = dpp_add<0x118, 0xf>(v);   // row_shr:8  -> row16-local inclusive
    v = dpp_add<0x142, 0xa>(v);   // row_bcast:15 -> rows 1,3
    v = dpp_add<0x143, 0xc>(v);   // row_bcast:31 -> rows 2,3
    return v;
}

// ---------------------------------------------------------------------------
// Kernel 1: depthwise 5x5 conv (pad=2) + bias + SiLU  (unchanged)
// ---------------------------------------------------------------------------
#define TS 76
__global__ __launch_bounds__(256) void conv_silu_kernel(
    const float* __restrict__ x, const float* __restrict__ conv_w,
    const float* __restrict__ conv_b, float* __restrict__ xs)
{
    __shared__ float tile[68 * TS];   // pixel(gh,gw) at [gh+2][gw+4]
    const int t = threadIdx.x;
    const int bd = blockIdx.x;
    const int d = bd % D_CH;          // block-uniform -> weights via s_load
    const float* img = x + bd * L_SZ;

    float wreg[25];
#pragma unroll
    for (int i = 0; i < 25; ++i) wreg[i] = conv_w[d * 25 + i];
    const float bias = conv_b[d];

    const float4 z4 = make_float4(0.f, 0.f, 0.f, 0.f);
    for (int i = t; i < 68 * TS / 4; i += 256) ((float4*)tile)[i] = z4;
    __syncthreads();
    for (int i = t; i < 1024; i += 256) {
        const int r = i >> 4;
        const int c = (i & 15) << 2;
        const float4 v = *(const float4*)(img + (r << 6) + c);
        *(float4*)(tile + (r + 2) * TS + 4 + c) = v;
    }
    __syncthreads();

    const int hr = t >> 2;
    const int cb = (t & 3) << 4;

    float acc[16];
#pragma unroll
    for (int j = 0; j < 16; ++j) acc[j] = bias;

#pragma unroll
    for (int kh = 0; kh < 5; ++kh) {
        const float* rp = tile + (hr + kh) * TS + cb;
        float r24[24];
#pragma unroll
        for (int q = 0; q < 6; ++q) {
            const float4 v = ((const float4*)rp)[q];
            r24[4*q+0] = v.x; r24[4*q+1] = v.y; r24[4*q+2] = v.z; r24[4*q+3] = v.w;
        }
#pragma unroll
        for (int j = 0; j < 16; ++j)
#pragma unroll
            for (int kw = 0; kw < 5; ++kw)
                acc[j] += wreg[kh * 5 + kw] * r24[j + kw + 2];
    }

    float* out = xs + bd * L_SZ + (hr << 6) + cb;
#pragma unroll
    for (int q = 0; q < 4; ++q) {
        float4 v;
#pragma unroll
        for (int j = 0; j < 4; ++j) {
            const float a = acc[4*q + j];
            const float s = __builtin_amdgcn_rcpf(1.0f + __expf(-a));
            (&v.x)[j] = a * s;
        }
        ((float4*)out)[q] = v;
    }
}

// ---------------------------------------------------------------------------
// Kernel 2: x_dbl[b,k,l] = sum_d x_proj_w[k,d] * xs[b,d,l]  (unchanged)
// ---------------------------------------------------------------------------
__global__ __launch_bounds__(256) void proj_kernel(
    const float* __restrict__ xs, const float* __restrict__ x_proj_w,
    float* __restrict__ x_dbl)
{
    __shared__ float red[4][14][64];
    const int t = threadIdx.x;
    const int g = t >> 6;
    const int ll = t & 63;
    const int bi = blockIdx.x;
    const int b = bi >> 6;
    const int chunk = bi & 63;
    const int l = (chunk << 6) + ll;
    const int d0 = __builtin_amdgcn_readfirstlane(g * 24);

    const float* xsb = xs + (b * D_CH + d0) * L_SZ + l;
    float acc[14];
#pragma unroll
    for (int k = 0; k < 14; ++k) acc[k] = 0.0f;

#pragma unroll
    for (int dd = 0; dd < 24; ++dd) {
        const float xv = xsb[dd * L_SZ];
#pragma unroll
        for (int k = 0; k < 14; ++k)
            acc[k] += x_proj_w[k * D_CH + d0 + dd] * xv;
    }

#pragma unroll
    for (int k = 0; k < 14; ++k) red[g][k][ll] = acc[k];
    __syncthreads();

    float* outb = x_dbl + b * 14 * L_SZ + (chunk << 6);
    for (int i = t; i < 14 * 64; i += 256) {
        const int k = i >> 6;
        const int c = i & 63;
        outb[k * L_SZ + c] = red[0][k][c] + red[1][k][c] + red[2][k][c] + red[3][k][c];
    }
}

// ---------------------------------------------------------------------------
// Kernel 3: selective scan (reference cumsum-trick, exact formulation)
// one block per (b,d); 512 threads x 8 contiguous l each.
// v2: DPP wave scans (no ds_bpermute), 5 barriers (was 8), log2-space exp
//     (An2 = A*log2e, clamp log2(EPS)), dl*xv hoisted, ex1 folded into the
//     running-sum init, yac pre-seeded with xs*Ds.
// ---------------------------------------------------------------------------
__global__ __launch_bounds__(512, 4) void scan_kernel(
    const float* __restrict__ xs, const float* __restrict__ x_dbl,
    const float* __restrict__ dt_w, const float* __restrict__ dt_b,
    const float* __restrict__ A_logs, const float* __restrict__ Ds,
    float* __restrict__ y)
{
    constexpr float L2EPS = -29.897352853986263f;   // log2(1e-9)
    constexpr float L2E   = 1.4426950408889634f;    // log2(e)

    __shared__ float4 s1[8];        // [wave] -> 4 per-n scan1 wave totals
    __shared__ float  s2[N_ST][8];  // per-n scan2 wave totals

    const int t    = threadIdx.x;
    const int lane = t & 63;
    const int wid  = t >> 6;
    const int bd = blockIdx.x;
    const int b = bd / D_CH;
    const int d = bd - b * D_CH;
    const int l0 = t * 8;

    const float* xs_row = xs + bd * L_SZ + l0;
    const float* xd = x_dbl + b * 14 * L_SZ + l0;

    float xv[8];
#pragma unroll
    for (int i = 0; i < 2; ++i) {
        const float4 v = ((const float4*)xs_row)[i];
        xv[4*i+0] = v.x; xv[4*i+1] = v.y; xv[4*i+2] = v.z; xv[4*i+3] = v.w;
    }

    // ---- delta = softplus(dt_w @ dts + dt_b) ----
    const float dtb = dt_b[d];
    float dl[8];
#pragma unroll
    for (int i = 0; i < 8; ++i) dl[i] = dtb;
#pragma unroll
    for (int r = 0; r < R_RK; ++r) {
        const float wr = dt_w[d * R_RK + r];          // uniform -> s_load
        const float* row = xd + r * L_SZ;
#pragma unroll
        for (int i = 0; i < 2; ++i) {
            const float4 v = ((const float4*)row)[i];
            dl[4*i+0] += wr * v.x; dl[4*i+1] += wr * v.y;
            dl[4*i+2] += wr * v.z; dl[4*i+3] += wr * v.w;
        }
    }
#pragma unroll
    for (int i = 0; i < 8; ++i) dl[i] = softplus_f(dl[i]);

    // hoist dl*xv; seed yac with the skip term so xv dies here
    const float dsd = Ds[d];
    float dlxv[8], yac[8];
#pragma unroll
    for (int i = 0; i < 8; ++i) { dlxv[i] = dl[i] * xv[i]; yac[i] = xv[i] * dsd; }

    float An2[N_ST];
#pragma unroll
    for (int n = 0; n < N_ST; ++n)
        An2[n] = -__expf(A_logs[d * N_ST + n]) * L2E;   // A * log2e (uniform)

    // ---- phase 1: all 4 log-cumsum totals, ONE barrier ----
    float exw1[N_ST];
    float4 w4;
#pragma unroll
    for (int n = 0; n < N_ST; ++n) {
        float run = 0.0f;
#pragma unroll
        for (int i = 0; i < 8; ++i) run += fmaxf(dl[i] * An2[n], L2EPS);
        const float incl = wave_incl_scan(run);
        exw1[n] = incl - run;                 // wave-local exclusive prefix
        (&w4.x)[n] = incl;
    }
    if (lane == 63) s1[wid] = w4;
    __syncthreads();

    float ex1[N_ST];
    {
        float4 wp = make_float4(0.f, 0.f, 0.f, 0.f);
#pragma unroll
        for (int w = 0; w < 7; ++w)
            if (w < wid) {                    // wid wave-uniform
                const float4 v = s1[w];
                wp.x += v.x; wp.y += v.y; wp.z += v.z; wp.w += v.w;
            }
        ex1[0] = wp.x + exw1[0]; ex1[1] = wp.y + exw1[1];
        ex1[2] = wp.z + exw1[2]; ex1[3] = wp.w + exw1[3];
    }

    // ---- phase 2: per n, pipelined (output(n-1)+passA(n) between barriers)
#pragma unroll
    for (int n = 0; n < N_ST; ++n) {
        const float* Brow = xd + (R_RK + n) * L_SZ;
        const float* Crow = xd + (R_RK + N_ST + n) * L_SZ;

        float carr[8], P[8];
        float run  = ex1[n];                  // ex1 folded into cumsum init
        float run2 = 0.0f;
#pragma unroll
        for (int i = 0; i < 2; ++i) {
            const float4 v = ((const float4*)Brow)[i];
            const float bb[4] = {v.x, v.y, v.z, v.w};
#pragma unroll
            for (int j = 0; j < 4; ++j) {
                const int idx = 4*i + j;
                run += fmaxf(dl[idx] * An2[n], L2EPS);   // S2 (log2 space)
                const float e = exp2_fast(-run);         // exp(-S) >= 1
                const float pinv = fminf(e, 1e9f);       // 1/max(P,EPS)
                P[idx] = __builtin_amdgcn_rcpf(e);       // exp(S)
                run2 = fmaf(dlxv[idx] * bb[j], pinv, run2);
                carr[idx] = run2;
            }
        }

        // prefetch C rows so their latency hides under scan+barrier
        const float4 c0 = ((const float4*)Crow)[0];
        const float4 c1 = ((const float4*)Crow)[1];

        const float incl = wave_incl_scan(run2);
        const float exw2 = incl - run2;
        if (lane == 63) s2[n][wid] = incl;
        __syncthreads();

        float wp2 = 0.0f;
#pragma unroll
        for (int w = 0; w < 7; ++w)
            if (w < wid) wp2 += s2[n][w];
        const float ex2 = wp2 + exw2;

        const float cc[8] = {c0.x, c0.y, c0.z, c0.w, c1.x, c1.y, c1.z, c1.w};
#pragma unroll
        for (int i = 0; i < 8; ++i)
            yac[i] = fmaf(P[i] * (carr[i] + ex2), cc[i], yac[i]);
    }

    float* yrow = y + bd * L_SZ + l0;
#pragma unroll
    for (int i = 0; i < 2; ++i) {
        float4 v;
        v.x = yac[4*i+0]; v.y = yac[4*i+1];
        v.z = yac[4*i+2]; v.w = yac[4*i+3];
        ((float4*)yrow)[i] = v;
    }
}

// ---------------------------------------------------------------------------
extern "C" void kernel_launch(void* const* d_in, const int* in_sizes, int n_in,
                              void* d_out, int out_size, void* d_ws, size_t ws_size,
                              hipStream_t stream)
{
    const float* x        = (const float*)d_in[0];
    const float* conv_w   = (const float*)d_in[1];
    const float* conv_b   = (const float*)d_in[2];
    const float* x_proj_w = (const float*)d_in[3];
    const float* dt_w     = (const float*)d_in[4];
    const float* dt_b     = (const float*)d_in[5];
    const float* A_logs   = (const float*)d_in[6];
    const float* Ds       = (const float*)d_in[7];

    float* y     = (float*)d_out;
    float* xs    = y;                 // stage conv output in d_out; scan reads
                                      // and overwrites it thread-privately
    float* x_dbl = (float*)d_ws;      // 32*14*4096 floats = 7.34 MB

    conv_silu_kernel<<<B_SZ * D_CH, 256, 0, stream>>>(x, conv_w, conv_b, xs);
    proj_kernel<<<B_SZ * 64, 256, 0, stream>>>(xs, x_proj_w, x_dbl);
    scan_kernel<<<B_SZ * D_CH, 512, 0, stream>>>(xs, x_dbl, dt_w, dt_b,
                                                 A_logs, Ds, y);
}

// Round 2
// 84.102 us; speedup vs baseline: 1.3216x; 1.3216x over previous
//
#include <hip/hip_runtime.h>

#define B_SZ 32
#define D_CH 96
#define L_SZ 4096   // 64*64
#define N_ST 4
#define R_RK 6

static __device__ __forceinline__ float softplus_f(float v) {
    return fmaxf(v, 0.0f) + __logf(1.0f + __expf(-fabsf(v)));
}

static __device__ __forceinline__ float exp2_fast(float x) {
#if __has_builtin(__builtin_amdgcn_exp2f)
    return __builtin_amdgcn_exp2f(x);      // v_exp_f32 (native 2^x)
#else
    return __expf(x * 0.6931471805599453f);
#endif
}

// DPP-shifted add: v + dpp(v); no LDS, no lgkm wait.
template<int CTRL, int RMASK>
static __device__ __forceinline__ float dpp_add(float v) {
    const int t = __builtin_amdgcn_update_dpp(0, __float_as_int(v),
                                              CTRL, RMASK, 0xf, true);
    return v + __int_as_float(t);
}

// wave64 inclusive scan (classic 6-step GCN sequence), pure VALU.
static __device__ __forceinline__ float wave_incl_scan(float v) {
    v = dpp_add<0x111, 0xf>(v);   // row_shr:1
    v = dpp_add<0x112, 0xf>(v);   // row_shr:2
    v = dpp_add<0x114, 0xf>(v);   // row_shr:4
    v = dpp_add<0x118, 0xf>(v);   // row_shr:8  -> row16-local inclusive
    v = dpp_add<0x142, 0xa>(v);   // row_bcast:15 -> rows 1,3
    v = dpp_add<0x143, 0xc>(v);   // row_bcast:31 -> rows 2,3
    return v;
}

// block exclusive scan (512 thr, 8 waves), ONE barrier, disjoint LDS slot.
// DPP wave scan, exclusive via incl - v (no extra shuffle).
static __device__ __forceinline__ float block_excl_scan(float v, float* slot, int t)
{
    const int lane = t & 63;
    const int wid  = t >> 6;
    const float incl = wave_incl_scan(v);
    if (lane == 63) slot[wid] = incl;
    const float ex = incl - v;
    __syncthreads();
    float wp = 0.0f;
#pragma unroll
    for (int w = 0; w < 7; ++w)
        if (w < wid) wp += slot[w];        // wid is wave-uniform
    return wp + ex;
}

// ---------------------------------------------------------------------------
// Kernel 1: depthwise 5x5 conv (pad=2) + bias + SiLU  (unchanged)
// ---------------------------------------------------------------------------
#define TS 76
__global__ __launch_bounds__(256) void conv_silu_kernel(
    const float* __restrict__ x, const float* __restrict__ conv_w,
    const float* __restrict__ conv_b, float* __restrict__ xs)
{
    __shared__ float tile[68 * TS];   // pixel(gh,gw) at [gh+2][gw+4]
    const int t = threadIdx.x;
    const int bd = blockIdx.x;
    const int d = bd % D_CH;          // block-uniform -> weights via s_load
    const float* img = x + bd * L_SZ;

    float wreg[25];
#pragma unroll
    for (int i = 0; i < 25; ++i) wreg[i] = conv_w[d * 25 + i];
    const float bias = conv_b[d];

    const float4 z4 = make_float4(0.f, 0.f, 0.f, 0.f);
    for (int i = t; i < 68 * TS / 4; i += 256) ((float4*)tile)[i] = z4;
    __syncthreads();
    for (int i = t; i < 1024; i += 256) {
        const int r = i >> 4;
        const int c = (i & 15) << 2;
        const float4 v = *(const float4*)(img + (r << 6) + c);
        *(float4*)(tile + (r + 2) * TS + 4 + c) = v;
    }
    __syncthreads();

    const int hr = t >> 2;
    const int cb = (t & 3) << 4;

    float acc[16];
#pragma unroll
    for (int j = 0; j < 16; ++j) acc[j] = bias;

#pragma unroll
    for (int kh = 0; kh < 5; ++kh) {
        const float* rp = tile + (hr + kh) * TS + cb;
        float r24[24];
#pragma unroll
        for (int q = 0; q < 6; ++q) {
            const float4 v = ((const float4*)rp)[q];
            r24[4*q+0] = v.x; r24[4*q+1] = v.y; r24[4*q+2] = v.z; r24[4*q+3] = v.w;
        }
#pragma unroll
        for (int j = 0; j < 16; ++j)
#pragma unroll
            for (int kw = 0; kw < 5; ++kw)
                acc[j] += wreg[kh * 5 + kw] * r24[j + kw + 2];
    }

    float* out = xs + bd * L_SZ + (hr << 6) + cb;
#pragma unroll
    for (int q = 0; q < 4; ++q) {
        float4 v;
#pragma unroll
        for (int j = 0; j < 4; ++j) {
            const float a = acc[4*q + j];
            const float s = __builtin_amdgcn_rcpf(1.0f + __expf(-a));
            (&v.x)[j] = a * s;
        }
        ((float4*)out)[q] = v;
    }
}

// ---------------------------------------------------------------------------
// Kernel 2: x_dbl[b,k,l] = sum_d x_proj_w[k,d] * xs[b,d,l]  (unchanged)
// ---------------------------------------------------------------------------
__global__ __launch_bounds__(256) void proj_kernel(
    const float* __restrict__ xs, const float* __restrict__ x_proj_w,
    float* __restrict__ x_dbl)
{
    __shared__ float red[4][14][64];
    const int t = threadIdx.x;
    const int g = t >> 6;
    const int ll = t & 63;
    const int bi = blockIdx.x;
    const int b = bi >> 6;
    const int chunk = bi & 63;
    const int l = (chunk << 6) + ll;
    const int d0 = __builtin_amdgcn_readfirstlane(g * 24);

    const float* xsb = xs + (b * D_CH + d0) * L_SZ + l;
    float acc[14];
#pragma unroll
    for (int k = 0; k < 14; ++k) acc[k] = 0.0f;

#pragma unroll
    for (int dd = 0; dd < 24; ++dd) {
        const float xv = xsb[dd * L_SZ];
#pragma unroll
        for (int k = 0; k < 14; ++k)
            acc[k] += x_proj_w[k * D_CH + d0 + dd] * xv;
    }

#pragma unroll
    for (int k = 0; k < 14; ++k) red[g][k][ll] = acc[k];
    __syncthreads();

    float* outb = x_dbl + b * 14 * L_SZ + (chunk << 6);
    for (int i = t; i < 14 * 64; i += 256) {
        const int k = i >> 6;
        const int c = i & 63;
        outb[k * L_SZ + c] = red[0][k][c] + red[1][k][c] + red[2][k][c] + red[3][k][c];
    }
}

// ---------------------------------------------------------------------------
// Kernel 3: selective scan (reference cumsum-trick, exact formulation)
// one block per (b,d); 512 threads x 8 contiguous l each.
// v3 = v1 dataflow (per-n loop, transient scan state, 8 barriers, 32-VGPR
//      shape) + register-neutral wins from v2:
//      - DPP wave scan (no ds_bpermute, no lgkm waits)
//      - log2-space exp (An2 = A*log2e, clamp log2(EPS), v_exp w/ neg mod)
//      - dlxv hoist + yac seeded with xs*Ds (xv dies in prologue)
// no phase batching, no prefetch, no persistent per-n arrays (those crossed
// the 64-VGPR occupancy cliff in v2: 67% -> 38%).
// ---------------------------------------------------------------------------
__global__ __launch_bounds__(512, 4) void scan_kernel(
    const float* __restrict__ xs, const float* __restrict__ x_dbl,
    const float* __restrict__ dt_w, const float* __restrict__ dt_b,
    const float* __restrict__ A_logs, const float* __restrict__ Ds,
    float* __restrict__ y)
{
    constexpr float L2EPS = -29.897352853986263f;   // log2(1e-9)
    constexpr float L2E   = 1.4426950408889634f;    // log2(e)

    __shared__ float slots[8][8];     // one 8-entry slot per block-scan call
    const int t = threadIdx.x;
    const int bd = blockIdx.x;
    const int b = bd / D_CH;
    const int d = bd - b * D_CH;
    const int l0 = t * 8;

    const float* xs_row = xs + bd * L_SZ + l0;
    const float* xd = x_dbl + b * 14 * L_SZ + l0;

    float xv[8];
#pragma unroll
    for (int i = 0; i < 2; ++i) {
        const float4 v = ((const float4*)xs_row)[i];
        xv[4*i+0] = v.x; xv[4*i+1] = v.y; xv[4*i+2] = v.z; xv[4*i+3] = v.w;
    }

    // ---- delta = softplus(dt_w @ dts + dt_b) ----
    const float dtb = dt_b[d];
    float dl[8];
#pragma unroll
    for (int i = 0; i < 8; ++i) dl[i] = dtb;
#pragma unroll
    for (int r = 0; r < R_RK; ++r) {
        const float wr = dt_w[d * R_RK + r];          // uniform -> s_load
        const float* row = xd + r * L_SZ;
#pragma unroll
        for (int i = 0; i < 2; ++i) {
            const float4 v = ((const float4*)row)[i];
            dl[4*i+0] += wr * v.x; dl[4*i+1] += wr * v.y;
            dl[4*i+2] += wr * v.z; dl[4*i+3] += wr * v.w;
        }
    }
#pragma unroll
    for (int i = 0; i < 8; ++i) dl[i] = softplus_f(dl[i]);

    // hoist dl*xv; seed yac with skip term so xv dies here (fewer live than v1)
    const float dsd = Ds[d];
    float dlxv[8], yac[8];
#pragma unroll
    for (int i = 0; i < 8; ++i) { dlxv[i] = dl[i] * xv[i]; yac[i] = xv[i] * dsd; }

    for (int n = 0; n < N_ST; ++n) {
        const float An2 = -__expf(A_logs[d * N_ST + n]) * L2E;  // uniform, transient

        // ---- local cumsum of log2_dA -> SP holds S (local) ----
        float SP[8];
        float run = 0.0f;
#pragma unroll
        for (int i = 0; i < 8; ++i) {
            run += fmaxf(dl[i] * An2, L2EPS);
            SP[i] = run;
        }
        const float ex1 = block_excl_scan(run, slots[2*n], t);

        // ---- cumsum of dB_u * pinv; SP becomes P ----
        const float* Brow = xd + (R_RK + n) * L_SZ;
        float carr[8];
        float run2 = 0.0f;
#pragma unroll
        for (int i = 0; i < 2; ++i) {
            const float4 v = ((const float4*)Brow)[i];
            const float bb[4] = {v.x, v.y, v.z, v.w};
#pragma unroll
            for (int j = 0; j < 4; ++j) {
                const int idx = 4*i + j;
                const float S = SP[idx] + ex1;           // log2-space S <= 0
                const float e = exp2_fast(-S);           // exp(-S) >= 1
                const float pinv = fminf(e, 1e9f);       // 1/max(P,EPS)
                SP[idx] = __builtin_amdgcn_rcpf(e);      // = exp(S) = P
                run2 = fmaf(dlxv[idx] * bb[j], pinv, run2);
                carr[idx] = run2;
            }
        }
        const float ex2 = block_excl_scan(run2, slots[2*n+1], t);

        const float* Crow = xd + (R_RK + N_ST + n) * L_SZ;
#pragma unroll
        for (int i = 0; i < 2; ++i) {
            const float4 v = ((const float4*)Crow)[i];
            const float cc[4] = {v.x, v.y, v.z, v.w};
#pragma unroll
            for (int j = 0; j < 4; ++j) {
                const int idx = 4*i + j;
                yac[idx] = fmaf(SP[idx] * (carr[idx] + ex2), cc[j], yac[idx]);
            }
        }
    }

    float* yrow = y + bd * L_SZ + l0;
#pragma unroll
    for (int i = 0; i < 2; ++i) {
        float4 v;
        v.x = yac[4*i+0]; v.y = yac[4*i+1];
        v.z = yac[4*i+2]; v.w = yac[4*i+3];
        ((float4*)yrow)[i] = v;
    }
}

// ---------------------------------------------------------------------------
extern "C" void kernel_launch(void* const* d_in, const int* in_sizes, int n_in,
                              void* d_out, int out_size, void* d_ws, size_t ws_size,
                              hipStream_t stream)
{
    const float* x        = (const float*)d_in[0];
    const float* conv_w   = (const float*)d_in[1];
    const float* conv_b   = (const float*)d_in[2];
    const float* x_proj_w = (const float*)d_in[3];
    const float* dt_w     = (const float*)d_in[4];
    const float* dt_b     = (const float*)d_in[5];
    const float* A_logs   = (const float*)d_in[6];
    const float* Ds       = (const float*)d_in[7];

    float* y     = (float*)d_out;
    float* xs    = y;                 // stage conv output in d_out; scan reads
                                      // and overwrites it thread-privately
    float* x_dbl = (float*)d_ws;      // 32*14*4096 floats = 7.34 MB

    conv_silu_kernel<<<B_SZ * D_CH, 256, 0, stream>>>(x, conv_w, conv_b, xs);
    proj_kernel<<<B_SZ * 64, 256, 0, stream>>>(xs, x_proj_w, x_dbl);
    scan_kernel<<<B_SZ * D_CH, 512, 0, stream>>>(xs, x_dbl, dt_w, dt_b,
                                                 A_logs, Ds, y);
}